// Round 1
// baseline (38378.799 us; speedup 1.0000x reference)
//
#include <hip/hip_runtime.h>
#include <hip/hip_bf16.h>

#define L_SEQ 1024
#define D_MODEL 768
#define D_INNER 1536
#define D_STATE 16
#define DT_RANK 48
#define N_LAYERS 24

// ---------------------------------------------------------------------------
// encode: u[t,d] = sum_i x[t,i]*w_enc[i,d] + b_enc[d]
// grid (3, 1024) x 256
__global__ __launch_bounds__(256) void encode_k(
    const float* __restrict__ x, const float* __restrict__ w_enc,
    const float* __restrict__ b_enc, float* __restrict__ u) {
  int d = blockIdx.x * 256 + threadIdx.x;  // 0..767
  int t = blockIdx.y;
  const float4 xv = *(const float4*)(x + t * 4);
  float acc = b_enc[d];
  acc = fmaf(xv.x, w_enc[0 * D_MODEL + d], acc);
  acc = fmaf(xv.y, w_enc[1 * D_MODEL + d], acc);
  acc = fmaf(xv.z, w_enc[2 * D_MODEL + d], acc);
  acc = fmaf(xv.w, w_enc[3 * D_MODEL + d], acc);
  u[t * D_MODEL + d] = acc;
}

// ---------------------------------------------------------------------------
// rmsnorm: h[t,:] = u[t,:] * rsqrt(mean(u^2)+eps) * w
// grid 1024 x 256
__global__ __launch_bounds__(256) void rmsnorm_k(
    const float* __restrict__ u, const float* __restrict__ w,
    float* __restrict__ h) {
  int t = blockIdx.x;
  const float* ur = u + t * D_MODEL;
  float ss = 0.f;
  for (int d = threadIdx.x; d < D_MODEL; d += 256) {
    float v = ur[d];
    ss = fmaf(v, v, ss);
  }
  #pragma unroll
  for (int o = 1; o < 64; o <<= 1) ss += __shfl_xor(ss, o);
  __shared__ float red[4];
  int wid = threadIdx.x >> 6;
  if ((threadIdx.x & 63) == 0) red[wid] = ss;
  __syncthreads();
  float tot = red[0] + red[1] + red[2] + red[3];
  float rs = rsqrtf(tot / (float)D_MODEL + 1e-5f);
  for (int d = threadIdx.x; d < D_MODEL; d += 256) {
    h[t * D_MODEL + d] = ur[d] * rs * w[d];
  }
}

// ---------------------------------------------------------------------------
// generic fp32 GEMM: C[M,N] = A[M,K] @ B[K,N]  (exact-tile grids, no guards)
// EPI: 0 = store, 1 = softplus(c + bias[n]), 2 = C += c (residual accumulate)
template <int BM, int BN, int BK, int TM, int TN, int EPI>
__global__ __launch_bounds__(256) void gemm_f32(
    const float* __restrict__ A, const float* __restrict__ B,
    float* __restrict__ C, int K, int lda, int ldb, int ldc,
    const float* __restrict__ bias) {
  __shared__ float As[BK][BM + 1];
  __shared__ float Bs[BK][BN + 1];
  const int tid = threadIdx.x;
  const int bm = blockIdx.y * BM;
  const int bn = blockIdx.x * BN;
  constexpr int TX = BN / TN;  // threads along n
  const int tx = tid % TX;
  const int ty = tid / TX;

  float acc[TM][TN];
  #pragma unroll
  for (int i = 0; i < TM; i++)
    #pragma unroll
    for (int j = 0; j < TN; j++) acc[i][j] = 0.f;

  for (int k0 = 0; k0 < K; k0 += BK) {
    for (int i = tid; i < BM * BK; i += 256) {
      int m = i / BK, k = i % BK;
      As[k][m] = A[(size_t)(bm + m) * lda + k0 + k];
    }
    for (int i = tid; i < BK * BN; i += 256) {
      int k = i / BN, n = i % BN;
      Bs[k][n] = B[(size_t)(k0 + k) * ldb + bn + n];
    }
    __syncthreads();
    #pragma unroll
    for (int k = 0; k < BK; k++) {
      float ra[TM], rb[TN];
      #pragma unroll
      for (int i = 0; i < TM; i++) ra[i] = As[k][ty * TM + i];
      #pragma unroll
      for (int j = 0; j < TN; j++) rb[j] = Bs[k][tx * TN + j];
      #pragma unroll
      for (int i = 0; i < TM; i++)
        #pragma unroll
        for (int j = 0; j < TN; j++) acc[i][j] = fmaf(ra[i], rb[j], acc[i][j]);
    }
    __syncthreads();
  }

  #pragma unroll
  for (int i = 0; i < TM; i++) {
    int m = bm + ty * TM + i;
    #pragma unroll
    for (int j = 0; j < TN; j++) {
      int n = bn + tx * TN + j;
      float v = acc[i][j];
      size_t idx = (size_t)m * ldc + n;
      if (EPI == 0) {
        C[idx] = v;
      } else if (EPI == 1) {
        v += bias[n];
        C[idx] = (v > 20.f) ? v : log1pf(__expf(v));
      } else {  // EPI == 2
        C[idx] += v;
      }
    }
  }
}

// ---------------------------------------------------------------------------
// causal depthwise conv (k=4) + bias + silu
// grid (6, 1024) x 256
__global__ __launch_bounds__(256) void conv_silu_k(
    const float* __restrict__ xz, const float* __restrict__ cw,
    const float* __restrict__ cb, float* __restrict__ xc) {
  int c = blockIdx.x * 256 + threadIdx.x;  // 0..1535
  int t = blockIdx.y;
  const float4 w = *(const float4*)(cw + c * 4);
  float acc = cb[c];
  if (t - 3 >= 0) acc = fmaf(xz[(t - 3) * 2 * D_INNER + c], w.x, acc);
  if (t - 2 >= 0) acc = fmaf(xz[(t - 2) * 2 * D_INNER + c], w.y, acc);
  if (t - 1 >= 0) acc = fmaf(xz[(t - 1) * 2 * D_INNER + c], w.z, acc);
  acc = fmaf(xz[t * 2 * D_INNER + c], w.w, acc);
  xc[t * D_INNER + c] = acc / (1.f + __expf(-acc));
}

// ---------------------------------------------------------------------------
// selective scan, fused with skip and silu(z) gating.
// one thread per (channel, state); 16 lanes (one channel) shuffle-reduce h.C
// grid 96 x 256
__global__ __launch_bounds__(256) void scan_k(
    const float* __restrict__ dt, const float* __restrict__ xc,
    const float* __restrict__ dbl, const float* __restrict__ xz,
    const float* __restrict__ A_log, const float* __restrict__ D_skip,
    float* __restrict__ y) {
  int tid = threadIdx.x;
  int s = tid & 15;
  int cl = tid >> 4;  // 0..15
  int c = blockIdx.x * 16 + cl;
  float a = -__expf(A_log[c * D_STATE + s]);
  float Dv = D_skip[c];
  float hst = 0.f;
  for (int t = 0; t < L_SEQ; t++) {
    float dtv = dt[t * D_INNER + c];
    float xv = xc[t * D_INNER + c];
    float Bv = dbl[t * 80 + DT_RANK + s];
    float Cv = dbl[t * 80 + DT_RANK + D_STATE + s];
    float dA = __expf(dtv * a);
    hst = fmaf(dA, hst, dtv * Bv * xv);
    float p = hst * Cv;
    p += __shfl_xor(p, 1);
    p += __shfl_xor(p, 2);
    p += __shfl_xor(p, 4);
    p += __shfl_xor(p, 8);
    if (s == 0) {
      float zv = xz[t * 2 * D_INNER + D_INNER + c];
      float sz = zv / (1.f + __expf(-zv));
      y[t * D_INNER + c] = (p + Dv * xv) * sz;
    }
  }
}

// ---------------------------------------------------------------------------
// final: rmsnorm(u[1023]) @ fc_w + fc_b -> out[0..1]
// grid 1 x 256
__global__ __launch_bounds__(256) void final_k(
    const float* __restrict__ u, const float* __restrict__ nfw,
    const float* __restrict__ fcw, const float* __restrict__ fcb,
    float* __restrict__ out) {
  const float* ur = u + (size_t)(L_SEQ - 1) * D_MODEL;
  float ss = 0.f;
  for (int d = threadIdx.x; d < D_MODEL; d += 256) {
    float v = ur[d];
    ss = fmaf(v, v, ss);
  }
  #pragma unroll
  for (int o = 1; o < 64; o <<= 1) ss += __shfl_xor(ss, o);
  __shared__ float red[4];
  int wid = threadIdx.x >> 6;
  if ((threadIdx.x & 63) == 0) red[wid] = ss;
  __syncthreads();
  float tot = red[0] + red[1] + red[2] + red[3];
  float rs = rsqrtf(tot / (float)D_MODEL + 1e-5f);
  float a0 = 0.f, a1 = 0.f;
  for (int d = threadIdx.x; d < D_MODEL; d += 256) {
    float hn = ur[d] * rs * nfw[d];
    a0 = fmaf(hn, fcw[d * 2 + 0], a0);
    a1 = fmaf(hn, fcw[d * 2 + 1], a1);
  }
  #pragma unroll
  for (int o = 1; o < 64; o <<= 1) {
    a0 += __shfl_xor(a0, o);
    a1 += __shfl_xor(a1, o);
  }
  __shared__ float r0[4], r1[4];
  if ((threadIdx.x & 63) == 0) {
    r0[wid] = a0;
    r1[wid] = a1;
  }
  __syncthreads();
  if (threadIdx.x == 0) out[0] = r0[0] + r0[1] + r0[2] + r0[3] + fcb[0];
  if (threadIdx.x == 1) out[1] = r1[0] + r1[1] + r1[2] + r1[3] + fcb[1];
}

// ---------------------------------------------------------------------------
extern "C" void kernel_launch(void* const* d_in, const int* in_sizes, int n_in,
                              void* d_out, int out_size, void* d_ws,
                              size_t ws_size, hipStream_t stream) {
  const float* x      = (const float*)d_in[0];
  const float* w_enc  = (const float*)d_in[1];
  const float* b_enc  = (const float*)d_in[2];
  const float* norm_w = (const float*)d_in[3];
  const float* in_w   = (const float*)d_in[4];
  const float* conv_w = (const float*)d_in[5];
  const float* conv_b = (const float*)d_in[6];
  const float* xp_w   = (const float*)d_in[7];
  const float* dt_w   = (const float*)d_in[8];
  const float* dt_b   = (const float*)d_in[9];
  const float* A_log  = (const float*)d_in[10];
  const float* D_skip = (const float*)d_in[11];
  const float* out_w  = (const float*)d_in[12];
  const float* nf_w   = (const float*)d_in[13];
  const float* fc_w   = (const float*)d_in[14];
  const float* fc_b   = (const float*)d_in[15];
  float* out = (float*)d_out;

  float* u   = (float*)d_ws;
  float* h   = u   + (size_t)L_SEQ * D_MODEL;
  float* xzb = h   + (size_t)L_SEQ * D_MODEL;
  float* xcb = xzb + (size_t)L_SEQ * 2 * D_INNER;
  float* dbl = xcb + (size_t)L_SEQ * D_INNER;
  float* dtb = dbl + (size_t)L_SEQ * 80;
  float* yb  = dtb + (size_t)L_SEQ * D_INNER;

  encode_k<<<dim3(3, L_SEQ), 256, 0, stream>>>(x, w_enc, b_enc, u);

  for (int l = 0; l < N_LAYERS; l++) {
    const float* in_w_l  = in_w  + (size_t)l * D_MODEL * 2 * D_INNER;
    const float* cw_l    = conv_w + (size_t)l * D_INNER * 4;
    const float* cb_l    = conv_b + (size_t)l * D_INNER;
    const float* xp_w_l  = xp_w  + (size_t)l * D_INNER * 80;
    const float* dt_w_l  = dt_w  + (size_t)l * DT_RANK * D_INNER;
    const float* dt_b_l  = dt_b  + (size_t)l * D_INNER;
    const float* A_log_l = A_log + (size_t)l * D_INNER * D_STATE;
    const float* D_l     = D_skip + (size_t)l * D_INNER;
    const float* out_w_l = out_w + (size_t)l * D_INNER * D_MODEL;

    // h = rmsnorm(u) * norm_w
    rmsnorm_k<<<L_SEQ, 256, 0, stream>>>(u, norm_w + (size_t)l * D_MODEL, h);
    // xz = h @ in_w : M=1024 N=3072 K=768
    gemm_f32<128, 64, 16, 8, 4, 0><<<dim3(3072 / 64, 1024 / 128), 256, 0, stream>>>(
        h, in_w_l, xzb, D_MODEL, D_MODEL, 2 * D_INNER, 2 * D_INNER, nullptr);
    // xc = silu(conv(xpart) + cb)
    conv_silu_k<<<dim3(6, L_SEQ), 256, 0, stream>>>(xzb, cw_l, cb_l, xcb);
    // dbl = xc @ xp_w : M=1024 N=80 K=1536
    gemm_f32<16, 80, 16, 1, 5, 0><<<dim3(1, 1024 / 16), 256, 0, stream>>>(
        xcb, xp_w_l, dbl, D_INNER, D_INNER, 80, 80, nullptr);
    // dt = softplus(dbl[:, :48] @ dt_w + dt_b) : M=1024 N=1536 K=48
    gemm_f32<64, 64, 16, 4, 4, 1><<<dim3(1536 / 64, 1024 / 64), 256, 0, stream>>>(
        dbl, dt_w_l, dtb, DT_RANK, 80, D_INNER, D_INNER, dt_b_l);
    // selective scan + skip + silu(z) gate -> y
    scan_k<<<D_INNER / 16, 256, 0, stream>>>(dtb, xcb, dbl, xzb, A_log_l, D_l, yb);
    // u += y @ out_w : M=1024 N=768 K=1536
    gemm_f32<64, 64, 16, 4, 4, 2><<<dim3(768 / 64, 1024 / 64), 256, 0, stream>>>(
        yb, out_w_l, u, D_INNER, D_INNER, D_MODEL, D_MODEL, nullptr);
  }

  final_k<<<1, 256, 0, stream>>>(u, nf_w, fc_w, fc_b, out);
}

// Round 2
// 20281.123 us; speedup vs baseline: 1.8923x; 1.8923x over previous
//
#include <hip/hip_runtime.h>
#include <hip/hip_bf16.h>

#define L_SEQ 1024
#define D_MODEL 768
#define D_INNER 1536
#define D_STATE 16
#define DT_RANK 48
#define N_LAYERS 24

// ---------------------------------------------------------------------------
// encode: u[t,d] = sum_i x[t,i]*w_enc[i,d] + b_enc[d]
// grid (3, 1024) x 256
__global__ __launch_bounds__(256) void encode_k(
    const float* __restrict__ x, const float* __restrict__ w_enc,
    const float* __restrict__ b_enc, float* __restrict__ u) {
  int d = blockIdx.x * 256 + threadIdx.x;  // 0..767
  int t = blockIdx.y;
  const float4 xv = *(const float4*)(x + t * 4);
  float acc = b_enc[d];
  acc = fmaf(xv.x, w_enc[0 * D_MODEL + d], acc);
  acc = fmaf(xv.y, w_enc[1 * D_MODEL + d], acc);
  acc = fmaf(xv.z, w_enc[2 * D_MODEL + d], acc);
  acc = fmaf(xv.w, w_enc[3 * D_MODEL + d], acc);
  u[t * D_MODEL + d] = acc;
}

// ---------------------------------------------------------------------------
// rmsnorm: h[t,:] = u[t,:] * rsqrt(mean(u^2)+eps) * w
// grid 1024 x 256
__global__ __launch_bounds__(256) void rmsnorm_k(
    const float* __restrict__ u, const float* __restrict__ w,
    float* __restrict__ h) {
  int t = blockIdx.x;
  const float* ur = u + t * D_MODEL;
  float ss = 0.f;
  for (int d = threadIdx.x; d < D_MODEL; d += 256) {
    float v = ur[d];
    ss = fmaf(v, v, ss);
  }
  #pragma unroll
  for (int o = 1; o < 64; o <<= 1) ss += __shfl_xor(ss, o);
  __shared__ float red[4];
  int wid = threadIdx.x >> 6;
  if ((threadIdx.x & 63) == 0) red[wid] = ss;
  __syncthreads();
  float tot = red[0] + red[1] + red[2] + red[3];
  float rs = rsqrtf(tot / (float)D_MODEL + 1e-5f);
  for (int d = threadIdx.x; d < D_MODEL; d += 256) {
    h[t * D_MODEL + d] = ur[d] * rs * w[d];
  }
}

// ---------------------------------------------------------------------------
// generic fp32 GEMM: C[M,N] = A[M,K] @ B[K,N]  (exact-tile grids, no guards)
// EPI: 0 = store, 1 = softplus(c + bias[n]), 2 = C += c (residual accumulate)
template <int BM, int BN, int BK, int TM, int TN, int EPI>
__global__ __launch_bounds__(256) void gemm_f32(
    const float* __restrict__ A, const float* __restrict__ B,
    float* __restrict__ C, int K, int lda, int ldb, int ldc,
    const float* __restrict__ bias) {
  __shared__ float As[BK][BM + 1];
  __shared__ float Bs[BK][BN + 1];
  const int tid = threadIdx.x;
  const int bm = blockIdx.y * BM;
  const int bn = blockIdx.x * BN;
  constexpr int TX = BN / TN;  // threads along n
  const int tx = tid % TX;
  const int ty = tid / TX;

  float acc[TM][TN];
  #pragma unroll
  for (int i = 0; i < TM; i++)
    #pragma unroll
    for (int j = 0; j < TN; j++) acc[i][j] = 0.f;

  for (int k0 = 0; k0 < K; k0 += BK) {
    for (int i = tid; i < BM * BK; i += 256) {
      int m = i / BK, k = i % BK;
      As[k][m] = A[(size_t)(bm + m) * lda + k0 + k];
    }
    for (int i = tid; i < BK * BN; i += 256) {
      int k = i / BN, n = i % BN;
      Bs[k][n] = B[(size_t)(k0 + k) * ldb + bn + n];
    }
    __syncthreads();
    #pragma unroll
    for (int k = 0; k < BK; k++) {
      float ra[TM], rb[TN];
      #pragma unroll
      for (int i = 0; i < TM; i++) ra[i] = As[k][ty * TM + i];
      #pragma unroll
      for (int j = 0; j < TN; j++) rb[j] = Bs[k][tx * TN + j];
      #pragma unroll
      for (int i = 0; i < TM; i++)
        #pragma unroll
        for (int j = 0; j < TN; j++) acc[i][j] = fmaf(ra[i], rb[j], acc[i][j]);
    }
    __syncthreads();
  }

  #pragma unroll
  for (int i = 0; i < TM; i++) {
    int m = bm + ty * TM + i;
    #pragma unroll
    for (int j = 0; j < TN; j++) {
      int n = bn + tx * TN + j;
      float v = acc[i][j];
      size_t idx = (size_t)m * ldc + n;
      if (EPI == 0) {
        C[idx] = v;
      } else if (EPI == 1) {
        v += bias[n];
        C[idx] = (v > 20.f) ? v : log1pf(__expf(v));
      } else {  // EPI == 2
        C[idx] += v;
      }
    }
  }
}

// ---------------------------------------------------------------------------
// dbl GEMM (M=1024, N=80, K=1536) split-K partial kernel.
// grid (NSPLIT=8, 64) x 256; BM=16, BN=80, Kseg=192, BK=16, TM=1, TN=5
#define DBL_NS 8
#define DBL_KSEG (D_INNER / DBL_NS)  // 192
__global__ __launch_bounds__(256) void gemm_dbl_k(
    const float* __restrict__ A, const float* __restrict__ B,
    float* __restrict__ P) {
  __shared__ float As[16][17];
  __shared__ float Bs[16][80];
  const int tid = threadIdx.x;
  const int bm = blockIdx.y * 16;
  const int ks0 = blockIdx.x * DBL_KSEG;
  const int tx = tid % 16;  // n-group (5 cols each)
  const int ty = tid / 16;  // row 0..15

  float acc[5] = {0.f, 0.f, 0.f, 0.f, 0.f};

  for (int k0 = ks0; k0 < ks0 + DBL_KSEG; k0 += 16) {
    {
      int m = tid / 16, k = tid % 16;  // 256 elems, 1/thread
      As[k][m] = A[(size_t)(bm + m) * D_INNER + k0 + k];
    }
    for (int i = tid; i < 16 * 80; i += 256) {
      int k = i / 80, n = i % 80;
      Bs[k][n] = B[(size_t)(k0 + k) * 80 + n];
    }
    __syncthreads();
    #pragma unroll
    for (int k = 0; k < 16; k++) {
      float ra = As[k][ty];
      #pragma unroll
      for (int j = 0; j < 5; j++)
        acc[j] = fmaf(ra, Bs[k][tx * 5 + j], acc[j]);
    }
    __syncthreads();
  }

  float* p = P + ((size_t)blockIdx.x * L_SEQ + bm + ty) * 80 + tx * 5;
  #pragma unroll
  for (int j = 0; j < 5; j++) p[j] = acc[j];
}

// grid 320 x 256: dbl[i] = sum_ks P[ks][i]
__global__ __launch_bounds__(256) void dbl_reduce_k(
    const float* __restrict__ P, float* __restrict__ dbl) {
  int i = blockIdx.x * 256 + threadIdx.x;  // 0..81919
  float s = 0.f;
  #pragma unroll
  for (int ks = 0; ks < DBL_NS; ks++) s += P[(size_t)ks * L_SEQ * 80 + i];
  dbl[i] = s;
}

// ---------------------------------------------------------------------------
// causal depthwise conv (k=4) + bias + silu
// grid (6, 1024) x 256
__global__ __launch_bounds__(256) void conv_silu_k(
    const float* __restrict__ xz, const float* __restrict__ cw,
    const float* __restrict__ cb, float* __restrict__ xc) {
  int c = blockIdx.x * 256 + threadIdx.x;  // 0..1535
  int t = blockIdx.y;
  const float4 w = *(const float4*)(cw + c * 4);
  float acc = cb[c];
  if (t - 3 >= 0) acc = fmaf(xz[(t - 3) * 2 * D_INNER + c], w.x, acc);
  if (t - 2 >= 0) acc = fmaf(xz[(t - 2) * 2 * D_INNER + c], w.y, acc);
  if (t - 1 >= 0) acc = fmaf(xz[(t - 1) * 2 * D_INNER + c], w.z, acc);
  acc = fmaf(xz[t * 2 * D_INNER + c], w.w, acc);
  xc[t * D_INNER + c] = acc / (1.f + __expf(-acc));
}

// ---------------------------------------------------------------------------
// selective scan, LDS time-tiled, fused with skip and silu(z) gating.
// block = 256 threads = 16 channels x 16 states; grid 96.
// Stages TT=128 timesteps of dt/xc/z (16ch) + B/C into LDS per tile.
#define TT 128
__global__ __launch_bounds__(256) void scan_k(
    const float* __restrict__ dt, const float* __restrict__ xc,
    const float* __restrict__ dbl, const float* __restrict__ xz,
    const float* __restrict__ A_log, const float* __restrict__ D_skip,
    float* __restrict__ y) {
  __shared__ float s_dt[TT][16];
  __shared__ float s_xc[TT][16];
  __shared__ float s_z[TT][16];
  __shared__ float s_bc[TT][32];

  const int tid = threadIdx.x;
  const int s = tid & 15;
  const int cl = tid >> 4;  // 0..15
  const int c0 = blockIdx.x * 16;
  const int c = c0 + cl;

  const float a = -__expf(A_log[c * D_STATE + s]);
  const float Dv = D_skip[c];
  float hst = 0.f;

  // staging decomposition
  const int lc = tid & 15;  // channel col
  const int lt = tid >> 4;  // t_sub 0..15
  const int bj = tid & 31;  // B/C col
  const int bt = tid >> 5;  // t_sub 0..7

  for (int t0 = 0; t0 < L_SEQ; t0 += TT) {
    __syncthreads();  // protect LDS from lagging readers of previous tile
    #pragma unroll
    for (int p = 0; p < TT / 16; p++) {
      int t = lt + p * 16;
      size_t gt = (size_t)(t0 + t);
      s_dt[t][lc] = dt[gt * D_INNER + c0 + lc];
      s_xc[t][lc] = xc[gt * D_INNER + c0 + lc];
      s_z[t][lc] = xz[gt * 2 * D_INNER + D_INNER + c0 + lc];
    }
    #pragma unroll
    for (int p = 0; p < TT / 8; p++) {
      int t = bt + p * 8;
      s_bc[t][bj] = dbl[(size_t)(t0 + t) * 80 + DT_RANK + bj];
    }
    __syncthreads();

    for (int t = 0; t < TT; t++) {
      float dtv = s_dt[t][cl];
      float xv = s_xc[t][cl];
      float Bv = s_bc[t][s];
      float Cv = s_bc[t][16 + s];
      float dA = __expf(dtv * a);
      hst = fmaf(dA, hst, dtv * Bv * xv);
      float p2 = hst * Cv;
      p2 += __shfl_xor(p2, 1);
      p2 += __shfl_xor(p2, 2);
      p2 += __shfl_xor(p2, 4);
      p2 += __shfl_xor(p2, 8);
      if (s == 0) {
        float zv = s_z[t][cl];
        float sz = zv / (1.f + __expf(-zv));
        y[(size_t)(t0 + t) * D_INNER + c] = (p2 + Dv * xv) * sz;
      }
    }
  }
}

// ---------------------------------------------------------------------------
// final: rmsnorm(u[1023]) @ fc_w + fc_b -> out[0..1]
// grid 1 x 256
__global__ __launch_bounds__(256) void final_k(
    const float* __restrict__ u, const float* __restrict__ nfw,
    const float* __restrict__ fcw, const float* __restrict__ fcb,
    float* __restrict__ out) {
  const float* ur = u + (size_t)(L_SEQ - 1) * D_MODEL;
  float ss = 0.f;
  for (int d = threadIdx.x; d < D_MODEL; d += 256) {
    float v = ur[d];
    ss = fmaf(v, v, ss);
  }
  #pragma unroll
  for (int o = 1; o < 64; o <<= 1) ss += __shfl_xor(ss, o);
  __shared__ float red[4];
  int wid = threadIdx.x >> 6;
  if ((threadIdx.x & 63) == 0) red[wid] = ss;
  __syncthreads();
  float tot = red[0] + red[1] + red[2] + red[3];
  float rs = rsqrtf(tot / (float)D_MODEL + 1e-5f);
  float a0 = 0.f, a1 = 0.f;
  for (int d = threadIdx.x; d < D_MODEL; d += 256) {
    float hn = ur[d] * rs * nfw[d];
    a0 = fmaf(hn, fcw[d * 2 + 0], a0);
    a1 = fmaf(hn, fcw[d * 2 + 1], a1);
  }
  #pragma unroll
  for (int o = 1; o < 64; o <<= 1) {
    a0 += __shfl_xor(a0, o);
    a1 += __shfl_xor(a1, o);
  }
  __shared__ float r0[4], r1[4];
  if ((threadIdx.x & 63) == 0) {
    r0[wid] = a0;
    r1[wid] = a1;
  }
  __syncthreads();
  if (threadIdx.x == 0) out[0] = r0[0] + r0[1] + r0[2] + r0[3] + fcb[0];
  if (threadIdx.x == 1) out[1] = r1[0] + r1[1] + r1[2] + r1[3] + fcb[1];
}

// ---------------------------------------------------------------------------
extern "C" void kernel_launch(void* const* d_in, const int* in_sizes, int n_in,
                              void* d_out, int out_size, void* d_ws,
                              size_t ws_size, hipStream_t stream) {
  const float* x      = (const float*)d_in[0];
  const float* w_enc  = (const float*)d_in[1];
  const float* b_enc  = (const float*)d_in[2];
  const float* norm_w = (const float*)d_in[3];
  const float* in_w   = (const float*)d_in[4];
  const float* conv_w = (const float*)d_in[5];
  const float* conv_b = (const float*)d_in[6];
  const float* xp_w   = (const float*)d_in[7];
  const float* dt_w   = (const float*)d_in[8];
  const float* dt_b   = (const float*)d_in[9];
  const float* A_log  = (const float*)d_in[10];
  const float* D_skip = (const float*)d_in[11];
  const float* out_w  = (const float*)d_in[12];
  const float* nf_w   = (const float*)d_in[13];
  const float* fc_w   = (const float*)d_in[14];
  const float* fc_b   = (const float*)d_in[15];
  float* out = (float*)d_out;

  float* u   = (float*)d_ws;
  float* h   = u   + (size_t)L_SEQ * D_MODEL;
  float* xzb = h   + (size_t)L_SEQ * D_MODEL;
  float* xcb = xzb + (size_t)L_SEQ * 2 * D_INNER;
  float* dbl = xcb + (size_t)L_SEQ * D_INNER;
  float* dtb = dbl + (size_t)L_SEQ * 80;
  float* yb  = dtb + (size_t)L_SEQ * D_INNER;
  // yb (1024*1536 floats) doubles as the dbl split-K partial buffer
  // (needs 8*1024*80 = 655360 floats) before scan_k writes it.

  encode_k<<<dim3(3, L_SEQ), 256, 0, stream>>>(x, w_enc, b_enc, u);

  for (int l = 0; l < N_LAYERS; l++) {
    const float* in_w_l  = in_w  + (size_t)l * D_MODEL * 2 * D_INNER;
    const float* cw_l    = conv_w + (size_t)l * D_INNER * 4;
    const float* cb_l    = conv_b + (size_t)l * D_INNER;
    const float* xp_w_l  = xp_w  + (size_t)l * D_INNER * 80;
    const float* dt_w_l  = dt_w  + (size_t)l * DT_RANK * D_INNER;
    const float* dt_b_l  = dt_b  + (size_t)l * D_INNER;
    const float* A_log_l = A_log + (size_t)l * D_INNER * D_STATE;
    const float* D_l     = D_skip + (size_t)l * D_INNER;
    const float* out_w_l = out_w + (size_t)l * D_INNER * D_MODEL;

    // h = rmsnorm(u) * norm_w
    rmsnorm_k<<<L_SEQ, 256, 0, stream>>>(u, norm_w + (size_t)l * D_MODEL, h);
    // xz = h @ in_w : M=1024 N=3072 K=768
    gemm_f32<128, 64, 16, 8, 4, 0><<<dim3(3072 / 64, 1024 / 128), 256, 0, stream>>>(
        h, in_w_l, xzb, D_MODEL, D_MODEL, 2 * D_INNER, 2 * D_INNER, nullptr);
    // xc = silu(conv(xpart) + cb)
    conv_silu_k<<<dim3(6, L_SEQ), 256, 0, stream>>>(xzb, cw_l, cb_l, xcb);
    // dbl = xc @ xp_w : M=1024 N=80 K=1536 (split-K x8 + reduce)
    gemm_dbl_k<<<dim3(DBL_NS, L_SEQ / 16), 256, 0, stream>>>(xcb, xp_w_l, yb);
    dbl_reduce_k<<<(L_SEQ * 80) / 256, 256, 0, stream>>>(yb, dbl);
    // dt = softplus(dbl[:, :48] @ dt_w + dt_b) : M=1024 N=1536 K=48
    gemm_f32<64, 64, 16, 4, 4, 1><<<dim3(1536 / 64, 1024 / 64), 256, 0, stream>>>(
        dbl, dt_w_l, dtb, DT_RANK, 80, D_INNER, D_INNER, dt_b_l);
    // selective scan + skip + silu(z) gate -> y
    scan_k<<<D_INNER / 16, 256, 0, stream>>>(dtb, xcb, dbl, xzb, A_log_l, D_l, yb);
    // u += y @ out_w : M=1024 N=768 K=1536
    gemm_f32<64, 64, 16, 4, 4, 2><<<dim3(768 / 64, 1024 / 64), 256, 0, stream>>>(
        yb, out_w_l, u, D_INNER, D_INNER, D_MODEL, D_MODEL, nullptr);
  }

  final_k<<<1, 256, 0, stream>>>(u, nf_w, fc_w, fc_b, out);
}

// Round 3
// 12586.292 us; speedup vs baseline: 3.0493x; 1.6114x over previous
//
#include <hip/hip_runtime.h>
#include <hip/hip_bf16.h>

#define L_SEQ 1024
#define D_MODEL 768
#define D_INNER 1536
#define D_STATE 16
#define DT_RANK 48
#define N_LAYERS 24

typedef __attribute__((ext_vector_type(8))) short short8;
typedef __attribute__((ext_vector_type(4))) float f32x4;

// exact fp32 -> bf16_hi + bf16_lo split (truncation; residual is exact fp32)
__device__ inline void split8(const float* v, ushort* hi, ushort* lo) {
#pragma unroll
  for (int i = 0; i < 8; i++) {
    unsigned b = __float_as_uint(v[i]);
    hi[i] = (ushort)(b >> 16);
    float lof = v[i] - __uint_as_float(b & 0xFFFF0000u);
    lo[i] = (ushort)(__float_as_uint(lof) >> 16);
  }
}

// ---------------------------------------------------------------------------
// split-bf16 3-pass MFMA GEMM: C[M,N] = A[M,K] @ B[K,N], fp32 in/out,
// ~fp32 accuracy (C ~= Ahi*Bhi + Ahi*Blo + Alo*Bhi, fp32 accum).
// block = 256 thr = 4 waves (2x2), wave tile 32x32, block tile 64x64, BK=32.
// K may be non-multiple of 32 (zero-padded). Exact-tile M,N grids.
// EPI: 0 = store, 1 = softplus(c + bias[n]), 2 = C += c
template <int EPI>
__global__ __launch_bounds__(256) void gemm_mfma(
    const float* __restrict__ A, const float* __restrict__ B,
    float* __restrict__ C, int K, int lda, int ldb, int ldc,
    const float* __restrict__ bias) {
  constexpr int ST = 40;  // LDS row stride (ushorts) = 80 B: pad breaks conflicts
  __shared__ ushort As[2][64 * ST];  // [plane hi/lo][row m][k]
  __shared__ ushort Bs[2][64 * ST];  // [plane hi/lo][row n][k]  (B transposed)

  const int tid = threadIdx.x;
  const int bm = blockIdx.y * 64;
  const int bn = blockIdx.x * 64;
  const int lane = tid & 63;
  const int wid = tid >> 6;
  const int wm = wid & 1, wn = wid >> 1;
  const int r = lane & 15, g = lane >> 4;

  const int srow = tid >> 2, ska = tid & 3;  // A staging: row, k-chunk(8)
  const int sn = tid & 63, skb = tid >> 6;   // B staging: n, k-chunk(8)

  f32x4 acc[2][2] = {};

  for (int k0 = 0; k0 < K; k0 += 32) {
    __syncthreads();
    // ---- stage A[bm+0..63][k0..k0+31] -> As (hi/lo)
    {
      float av[8];
      const int kb = k0 + ska * 8;
#pragma unroll
      for (int j = 0; j < 8; j++) {
        int k = kb + j;
        av[j] = (k < K) ? A[(size_t)(bm + srow) * lda + k] : 0.f;
      }
      ushort hi[8], lo[8];
      split8(av, hi, lo);
      *reinterpret_cast<short8*>(&As[0][srow * ST + ska * 8]) =
          *reinterpret_cast<short8*>(hi);
      *reinterpret_cast<short8*>(&As[1][srow * ST + ska * 8]) =
          *reinterpret_cast<short8*>(lo);
    }
    // ---- stage B[k0..k0+31][bn+0..63] -> Bs transposed (hi/lo)
    {
      float bv[8];
#pragma unroll
      for (int j = 0; j < 8; j++) {
        int k = k0 + skb * 8 + j;
        bv[j] = (k < K) ? B[(size_t)k * ldb + bn + sn] : 0.f;
      }
      ushort hi[8], lo[8];
      split8(bv, hi, lo);
      *reinterpret_cast<short8*>(&Bs[0][sn * ST + skb * 8]) =
          *reinterpret_cast<short8*>(hi);
      *reinterpret_cast<short8*>(&Bs[1][sn * ST + skb * 8]) =
          *reinterpret_cast<short8*>(lo);
    }
    __syncthreads();

    // ---- fragments + 3-pass MFMA
    short8 a_hi[2], a_lo[2], b_hi[2], b_lo[2];
#pragma unroll
    for (int m = 0; m < 2; m++) {
      int row = wm * 32 + m * 16 + r;
      a_hi[m] = *reinterpret_cast<short8*>(&As[0][row * ST + g * 8]);
      a_lo[m] = *reinterpret_cast<short8*>(&As[1][row * ST + g * 8]);
    }
#pragma unroll
    for (int n = 0; n < 2; n++) {
      int row = wn * 32 + n * 16 + r;
      b_hi[n] = *reinterpret_cast<short8*>(&Bs[0][row * ST + g * 8]);
      b_lo[n] = *reinterpret_cast<short8*>(&Bs[1][row * ST + g * 8]);
    }
#pragma unroll
    for (int m = 0; m < 2; m++)
#pragma unroll
      for (int n = 0; n < 2; n++) {
        acc[m][n] = __builtin_amdgcn_mfma_f32_16x16x32_bf16(
            a_hi[m], b_hi[n], acc[m][n], 0, 0, 0);
        acc[m][n] = __builtin_amdgcn_mfma_f32_16x16x32_bf16(
            a_hi[m], b_lo[n], acc[m][n], 0, 0, 0);
        acc[m][n] = __builtin_amdgcn_mfma_f32_16x16x32_bf16(
            a_lo[m], b_hi[n], acc[m][n], 0, 0, 0);
      }
  }

  // ---- epilogue: D[row=(g*4+j)][col=r] per 16x16 fragment
#pragma unroll
  for (int m = 0; m < 2; m++) {
#pragma unroll
    for (int n = 0; n < 2; n++) {
      int row0 = bm + wm * 32 + m * 16 + g * 4;
      int col = bn + wn * 32 + n * 16 + r;
#pragma unroll
      for (int j = 0; j < 4; j++) {
        size_t idx = (size_t)(row0 + j) * ldc + col;
        float v = acc[m][n][j];
        if (EPI == 0) {
          C[idx] = v;
        } else if (EPI == 1) {
          v += bias[col];
          C[idx] = (v > 20.f) ? v : log1pf(__expf(v));
        } else {
          C[idx] += v;
        }
      }
    }
  }
}

// ---------------------------------------------------------------------------
// encode: u[t,d] = sum_i x[t,i]*w_enc[i,d] + b_enc[d]
__global__ __launch_bounds__(256) void encode_k(
    const float* __restrict__ x, const float* __restrict__ w_enc,
    const float* __restrict__ b_enc, float* __restrict__ u) {
  int d = blockIdx.x * 256 + threadIdx.x;
  int t = blockIdx.y;
  const float4 xv = *(const float4*)(x + t * 4);
  float acc = b_enc[d];
  acc = fmaf(xv.x, w_enc[0 * D_MODEL + d], acc);
  acc = fmaf(xv.y, w_enc[1 * D_MODEL + d], acc);
  acc = fmaf(xv.z, w_enc[2 * D_MODEL + d], acc);
  acc = fmaf(xv.w, w_enc[3 * D_MODEL + d], acc);
  u[t * D_MODEL + d] = acc;
}

// ---------------------------------------------------------------------------
__global__ __launch_bounds__(256) void rmsnorm_k(
    const float* __restrict__ u, const float* __restrict__ w,
    float* __restrict__ h) {
  int t = blockIdx.x;
  const float* ur = u + t * D_MODEL;
  float ss = 0.f;
  for (int d = threadIdx.x; d < D_MODEL; d += 256) {
    float v = ur[d];
    ss = fmaf(v, v, ss);
  }
#pragma unroll
  for (int o = 1; o < 64; o <<= 1) ss += __shfl_xor(ss, o);
  __shared__ float red[4];
  int wid = threadIdx.x >> 6;
  if ((threadIdx.x & 63) == 0) red[wid] = ss;
  __syncthreads();
  float tot = red[0] + red[1] + red[2] + red[3];
  float rs = rsqrtf(tot / (float)D_MODEL + 1e-5f);
  for (int d = threadIdx.x; d < D_MODEL; d += 256) {
    h[t * D_MODEL + d] = ur[d] * rs * w[d];
  }
}

// ---------------------------------------------------------------------------
// dbl GEMM (M=1024, N=80, K=1536) split-K partial kernel (fp32).
#define DBL_NS 8
#define DBL_KSEG (D_INNER / DBL_NS)  // 192
__global__ __launch_bounds__(256) void gemm_dbl_k(
    const float* __restrict__ A, const float* __restrict__ B,
    float* __restrict__ P) {
  __shared__ float As2[16][17];
  __shared__ float Bs2[16][80];
  const int tid = threadIdx.x;
  const int bm = blockIdx.y * 16;
  const int ks0 = blockIdx.x * DBL_KSEG;
  const int tx = tid % 16;
  const int ty = tid / 16;

  float acc[5] = {0.f, 0.f, 0.f, 0.f, 0.f};

  for (int k0 = ks0; k0 < ks0 + DBL_KSEG; k0 += 16) {
    {
      int m = tid / 16, k = tid % 16;
      As2[k][m] = A[(size_t)(bm + m) * D_INNER + k0 + k];
    }
    for (int i = tid; i < 16 * 80; i += 256) {
      int k = i / 80, n = i % 80;
      Bs2[k][n] = B[(size_t)(k0 + k) * 80 + n];
    }
    __syncthreads();
#pragma unroll
    for (int k = 0; k < 16; k++) {
      float ra = As2[k][ty];
#pragma unroll
      for (int j = 0; j < 5; j++) acc[j] = fmaf(ra, Bs2[k][tx * 5 + j], acc[j]);
    }
    __syncthreads();
  }

  float* p = P + ((size_t)blockIdx.x * L_SEQ + bm + ty) * 80 + tx * 5;
#pragma unroll
  for (int j = 0; j < 5; j++) p[j] = acc[j];
}

__global__ __launch_bounds__(256) void dbl_reduce_k(
    const float* __restrict__ P, float* __restrict__ dbl) {
  int i = blockIdx.x * 256 + threadIdx.x;
  float s = 0.f;
#pragma unroll
  for (int ks = 0; ks < DBL_NS; ks++) s += P[(size_t)ks * L_SEQ * 80 + i];
  dbl[i] = s;
}

// ---------------------------------------------------------------------------
// causal depthwise conv (k=4) + bias + silu
__global__ __launch_bounds__(256) void conv_silu_k(
    const float* __restrict__ xz, const float* __restrict__ cw,
    const float* __restrict__ cb, float* __restrict__ xc) {
  int c = blockIdx.x * 256 + threadIdx.x;
  int t = blockIdx.y;
  const float4 w = *(const float4*)(cw + c * 4);
  float acc = cb[c];
  if (t - 3 >= 0) acc = fmaf(xz[(t - 3) * 2 * D_INNER + c], w.x, acc);
  if (t - 2 >= 0) acc = fmaf(xz[(t - 2) * 2 * D_INNER + c], w.y, acc);
  if (t - 1 >= 0) acc = fmaf(xz[(t - 1) * 2 * D_INNER + c], w.z, acc);
  acc = fmaf(xz[t * 2 * D_INNER + c], w.w, acc);
  xc[t * D_INNER + c] = acc / (1.f + __expf(-acc));
}

// ---------------------------------------------------------------------------
// selective scan, LDS time-tiled, fused with skip and silu(z) gating.
#define TT 128
__global__ __launch_bounds__(256) void scan_k(
    const float* __restrict__ dt, const float* __restrict__ xc,
    const float* __restrict__ dbl, const float* __restrict__ xz,
    const float* __restrict__ A_log, const float* __restrict__ D_skip,
    float* __restrict__ y) {
  __shared__ float s_dt[TT][16];
  __shared__ float s_xc[TT][16];
  __shared__ float s_z[TT][16];
  __shared__ float s_bc[TT][32];

  const int tid = threadIdx.x;
  const int s = tid & 15;
  const int cl = tid >> 4;
  const int c0 = blockIdx.x * 16;
  const int c = c0 + cl;

  const float a = -__expf(A_log[c * D_STATE + s]);
  const float Dv = D_skip[c];
  float hst = 0.f;

  const int lc = tid & 15;
  const int lt = tid >> 4;
  const int bj = tid & 31;
  const int bt = tid >> 5;

  for (int t0 = 0; t0 < L_SEQ; t0 += TT) {
    __syncthreads();
#pragma unroll
    for (int p = 0; p < TT / 16; p++) {
      int t = lt + p * 16;
      size_t gt = (size_t)(t0 + t);
      s_dt[t][lc] = dt[gt * D_INNER + c0 + lc];
      s_xc[t][lc] = xc[gt * D_INNER + c0 + lc];
      s_z[t][lc] = xz[gt * 2 * D_INNER + D_INNER + c0 + lc];
    }
#pragma unroll
    for (int p = 0; p < TT / 8; p++) {
      int t = bt + p * 8;
      s_bc[t][bj] = dbl[(size_t)(t0 + t) * 80 + DT_RANK + bj];
    }
    __syncthreads();

    for (int t = 0; t < TT; t++) {
      float dtv = s_dt[t][cl];
      float xv = s_xc[t][cl];
      float Bv = s_bc[t][s];
      float Cv = s_bc[t][16 + s];
      float dA = __expf(dtv * a);
      hst = fmaf(dA, hst, dtv * Bv * xv);
      float p2 = hst * Cv;
      p2 += __shfl_xor(p2, 1);
      p2 += __shfl_xor(p2, 2);
      p2 += __shfl_xor(p2, 4);
      p2 += __shfl_xor(p2, 8);
      if (s == 0) {
        float zv = s_z[t][cl];
        float sz = zv / (1.f + __expf(-zv));
        y[(size_t)(t0 + t) * D_INNER + c] = (p2 + Dv * xv) * sz;
      }
    }
  }
}

// ---------------------------------------------------------------------------
__global__ __launch_bounds__(256) void final_k(
    const float* __restrict__ u, const float* __restrict__ nfw,
    const float* __restrict__ fcw, const float* __restrict__ fcb,
    float* __restrict__ out) {
  const float* ur = u + (size_t)(L_SEQ - 1) * D_MODEL;
  float ss = 0.f;
  for (int d = threadIdx.x; d < D_MODEL; d += 256) {
    float v = ur[d];
    ss = fmaf(v, v, ss);
  }
#pragma unroll
  for (int o = 1; o < 64; o <<= 1) ss += __shfl_xor(ss, o);
  __shared__ float red[4];
  int wid = threadIdx.x >> 6;
  if ((threadIdx.x & 63) == 0) red[wid] = ss;
  __syncthreads();
  float tot = red[0] + red[1] + red[2] + red[3];
  float rs = rsqrtf(tot / (float)D_MODEL + 1e-5f);
  float a0 = 0.f, a1 = 0.f;
  for (int d = threadIdx.x; d < D_MODEL; d += 256) {
    float hn = ur[d] * rs * nfw[d];
    a0 = fmaf(hn, fcw[d * 2 + 0], a0);
    a1 = fmaf(hn, fcw[d * 2 + 1], a1);
  }
#pragma unroll
  for (int o = 1; o < 64; o <<= 1) {
    a0 += __shfl_xor(a0, o);
    a1 += __shfl_xor(a1, o);
  }
  __shared__ float r0[4], r1[4];
  if ((threadIdx.x & 63) == 0) {
    r0[wid] = a0;
    r1[wid] = a1;
  }
  __syncthreads();
  if (threadIdx.x == 0) out[0] = r0[0] + r0[1] + r0[2] + r0[3] + fcb[0];
  if (threadIdx.x == 1) out[1] = r1[0] + r1[1] + r1[2] + r1[3] + fcb[1];
}

// ---------------------------------------------------------------------------
extern "C" void kernel_launch(void* const* d_in, const int* in_sizes, int n_in,
                              void* d_out, int out_size, void* d_ws,
                              size_t ws_size, hipStream_t stream) {
  const float* x      = (const float*)d_in[0];
  const float* w_enc  = (const float*)d_in[1];
  const float* b_enc  = (const float*)d_in[2];
  const float* norm_w = (const float*)d_in[3];
  const float* in_w   = (const float*)d_in[4];
  const float* conv_w = (const float*)d_in[5];
  const float* conv_b = (const float*)d_in[6];
  const float* xp_w   = (const float*)d_in[7];
  const float* dt_w   = (const float*)d_in[8];
  const float* dt_b   = (const float*)d_in[9];
  const float* A_log  = (const float*)d_in[10];
  const float* D_skip = (const float*)d_in[11];
  const float* out_w  = (const float*)d_in[12];
  const float* nf_w   = (const float*)d_in[13];
  const float* fc_w   = (const float*)d_in[14];
  const float* fc_b   = (const float*)d_in[15];
  float* out = (float*)d_out;

  float* u   = (float*)d_ws;
  float* h   = u   + (size_t)L_SEQ * D_MODEL;
  float* xzb = h   + (size_t)L_SEQ * D_MODEL;
  float* xcb = xzb + (size_t)L_SEQ * 2 * D_INNER;
  float* dbl = xcb + (size_t)L_SEQ * D_INNER;
  float* dtb = dbl + (size_t)L_SEQ * 80;
  float* yb  = dtb + (size_t)L_SEQ * D_INNER;
  // yb doubles as dbl split-K partial buffer (8*1024*80 floats) before scan_k.

  encode_k<<<dim3(3, L_SEQ), 256, 0, stream>>>(x, w_enc, b_enc, u);

  for (int l = 0; l < N_LAYERS; l++) {
    const float* in_w_l  = in_w  + (size_t)l * D_MODEL * 2 * D_INNER;
    const float* cw_l    = conv_w + (size_t)l * D_INNER * 4;
    const float* cb_l    = conv_b + (size_t)l * D_INNER;
    const float* xp_w_l  = xp_w  + (size_t)l * D_INNER * 80;
    const float* dt_w_l  = dt_w  + (size_t)l * DT_RANK * D_INNER;
    const float* dt_b_l  = dt_b  + (size_t)l * D_INNER;
    const float* A_log_l = A_log + (size_t)l * D_INNER * D_STATE;
    const float* D_l     = D_skip + (size_t)l * D_INNER;
    const float* out_w_l = out_w + (size_t)l * D_INNER * D_MODEL;

    // h = rmsnorm(u) * norm_w
    rmsnorm_k<<<L_SEQ, 256, 0, stream>>>(u, norm_w + (size_t)l * D_MODEL, h);
    // xz = h @ in_w : M=1024 N=3072 K=768
    gemm_mfma<0><<<dim3(3072 / 64, 1024 / 64), 256, 0, stream>>>(
        h, in_w_l, xzb, D_MODEL, D_MODEL, 2 * D_INNER, 2 * D_INNER, nullptr);
    // xc = silu(conv(xpart) + cb)
    conv_silu_k<<<dim3(6, L_SEQ), 256, 0, stream>>>(xzb, cw_l, cb_l, xcb);
    // dbl = xc @ xp_w : M=1024 N=80 K=1536 (split-K x8 + reduce, fp32)
    gemm_dbl_k<<<dim3(DBL_NS, L_SEQ / 16), 256, 0, stream>>>(xcb, xp_w_l, yb);
    dbl_reduce_k<<<(L_SEQ * 80) / 256, 256, 0, stream>>>(yb, dbl);
    // dt = softplus(dbl[:, :48] @ dt_w + dt_b) : M=1024 N=1536 K=48 (padded)
    gemm_mfma<1><<<dim3(1536 / 64, 1024 / 64), 256, 0, stream>>>(
        dbl, dt_w_l, dtb, DT_RANK, 80, D_INNER, D_INNER, dt_b_l);
    // selective scan + skip + silu(z) gate -> y
    scan_k<<<D_INNER / 16, 256, 0, stream>>>(dtb, xcb, dbl, xzb, A_log_l, D_l, yb);
    // u += y @ out_w : M=1024 N=768 K=1536
    gemm_mfma<2><<<dim3(768 / 64, 1024 / 64), 256, 0, stream>>>(
        yb, out_w_l, u, D_INNER, D_INNER, D_MODEL, D_MODEL, nullptr);
  }

  final_k<<<1, 256, 0, stream>>>(u, nf_w, fc_w, fc_b, out);
}

// Round 4
// 7517.830 us; speedup vs baseline: 5.1050x; 1.6742x over previous
//
#include <hip/hip_runtime.h>
#include <hip/hip_bf16.h>

#define L_SEQ 1024
#define D_MODEL 768
#define D_INNER 1536
#define D_STATE 16
#define DT_RANK 48
#define N_LAYERS 24
#define NCHUNK 8
#define CS (L_SEQ / NCHUNK)  // 128

typedef __attribute__((ext_vector_type(8))) short short8;
typedef __attribute__((ext_vector_type(4))) float f32x4;

// exact fp32 -> bf16_hi + bf16_lo split (truncation; residual is exact fp32)
__device__ inline void split8(const float* v, ushort* hi, ushort* lo) {
#pragma unroll
  for (int i = 0; i < 8; i++) {
    unsigned b = __float_as_uint(v[i]);
    hi[i] = (ushort)(b >> 16);
    float lof = v[i] - __uint_as_float(b & 0xFFFF0000u);
    lo[i] = (ushort)(__float_as_uint(lof) >> 16);
  }
}

// ---------------------------------------------------------------------------
// split-bf16 3-pass MFMA GEMM: C[M,N] = A[M,K] @ B[K,N], fp32 in/out,
// ~fp32 accuracy (C ~= Ahi*Bhi + Ahi*Blo + Alo*Bhi, fp32 accum).
// block = 256 thr = 4 waves (2x2), wave tile 32x32, block tile 64x64, BK=32.
// EPI: 0 = store, 1 = softplus(c + bias[n]), 2 = C += c
template <int EPI>
__global__ __launch_bounds__(256) void gemm_mfma(
    const float* __restrict__ A, const float* __restrict__ B,
    float* __restrict__ C, int K, int lda, int ldb, int ldc,
    const float* __restrict__ bias) {
  constexpr int ST = 40;  // LDS row stride (ushorts) = 80 B: pad breaks conflicts
  __shared__ ushort As[2][64 * ST];  // [plane hi/lo][row m][k]
  __shared__ ushort Bs[2][64 * ST];  // [plane hi/lo][row n][k]  (B transposed)

  const int tid = threadIdx.x;
  const int bm = blockIdx.y * 64;
  const int bn = blockIdx.x * 64;
  const int lane = tid & 63;
  const int wid = tid >> 6;
  const int wm = wid & 1, wn = wid >> 1;
  const int r = lane & 15, g = lane >> 4;

  const int srow = tid >> 2, ska = tid & 3;  // A staging: row, k-chunk(8)
  const int sn = tid & 63, skb = tid >> 6;   // B staging: n, k-chunk(8)

  f32x4 acc[2][2] = {};

  for (int k0 = 0; k0 < K; k0 += 32) {
    __syncthreads();
    {
      float av[8];
      const int kb = k0 + ska * 8;
#pragma unroll
      for (int j = 0; j < 8; j++) {
        int k = kb + j;
        av[j] = (k < K) ? A[(size_t)(bm + srow) * lda + k] : 0.f;
      }
      ushort hi[8], lo[8];
      split8(av, hi, lo);
      *reinterpret_cast<short8*>(&As[0][srow * ST + ska * 8]) =
          *reinterpret_cast<short8*>(hi);
      *reinterpret_cast<short8*>(&As[1][srow * ST + ska * 8]) =
          *reinterpret_cast<short8*>(lo);
    }
    {
      float bv[8];
#pragma unroll
      for (int j = 0; j < 8; j++) {
        int k = k0 + skb * 8 + j;
        bv[j] = (k < K) ? B[(size_t)k * ldb + bn + sn] : 0.f;
      }
      ushort hi[8], lo[8];
      split8(bv, hi, lo);
      *reinterpret_cast<short8*>(&Bs[0][sn * ST + skb * 8]) =
          *reinterpret_cast<short8*>(hi);
      *reinterpret_cast<short8*>(&Bs[1][sn * ST + skb * 8]) =
          *reinterpret_cast<short8*>(lo);
    }
    __syncthreads();

    short8 a_hi[2], a_lo[2], b_hi[2], b_lo[2];
#pragma unroll
    for (int m = 0; m < 2; m++) {
      int row = wm * 32 + m * 16 + r;
      a_hi[m] = *reinterpret_cast<short8*>(&As[0][row * ST + g * 8]);
      a_lo[m] = *reinterpret_cast<short8*>(&As[1][row * ST + g * 8]);
    }
#pragma unroll
    for (int n = 0; n < 2; n++) {
      int row = wn * 32 + n * 16 + r;
      b_hi[n] = *reinterpret_cast<short8*>(&Bs[0][row * ST + g * 8]);
      b_lo[n] = *reinterpret_cast<short8*>(&Bs[1][row * ST + g * 8]);
    }
#pragma unroll
    for (int m = 0; m < 2; m++)
#pragma unroll
      for (int n = 0; n < 2; n++) {
        acc[m][n] = __builtin_amdgcn_mfma_f32_16x16x32_bf16(
            a_hi[m], b_hi[n], acc[m][n], 0, 0, 0);
        acc[m][n] = __builtin_amdgcn_mfma_f32_16x16x32_bf16(
            a_hi[m], b_lo[n], acc[m][n], 0, 0, 0);
        acc[m][n] = __builtin_amdgcn_mfma_f32_16x16x32_bf16(
            a_lo[m], b_hi[n], acc[m][n], 0, 0, 0);
      }
  }

#pragma unroll
  for (int m = 0; m < 2; m++) {
#pragma unroll
    for (int n = 0; n < 2; n++) {
      int row0 = bm + wm * 32 + m * 16 + g * 4;
      int col = bn + wn * 32 + n * 16 + r;
#pragma unroll
      for (int j = 0; j < 4; j++) {
        size_t idx = (size_t)(row0 + j) * ldc + col;
        float v = acc[m][n][j];
        if (EPI == 0) {
          C[idx] = v;
        } else if (EPI == 1) {
          v += bias[col];
          C[idx] = (v > 20.f) ? v : log1pf(__expf(v));
        } else {
          C[idx] += v;
        }
      }
    }
  }
}

// ---------------------------------------------------------------------------
__global__ __launch_bounds__(256) void encode_k(
    const float* __restrict__ x, const float* __restrict__ w_enc,
    const float* __restrict__ b_enc, float* __restrict__ u) {
  int d = blockIdx.x * 256 + threadIdx.x;
  int t = blockIdx.y;
  const float4 xv = *(const float4*)(x + t * 4);
  float acc = b_enc[d];
  acc = fmaf(xv.x, w_enc[0 * D_MODEL + d], acc);
  acc = fmaf(xv.y, w_enc[1 * D_MODEL + d], acc);
  acc = fmaf(xv.z, w_enc[2 * D_MODEL + d], acc);
  acc = fmaf(xv.w, w_enc[3 * D_MODEL + d], acc);
  u[t * D_MODEL + d] = acc;
}

// ---------------------------------------------------------------------------
__global__ __launch_bounds__(256) void rmsnorm_k(
    const float* __restrict__ u, const float* __restrict__ w,
    float* __restrict__ h) {
  int t = blockIdx.x;
  const float* ur = u + t * D_MODEL;
  float ss = 0.f;
  for (int d = threadIdx.x; d < D_MODEL; d += 256) {
    float v = ur[d];
    ss = fmaf(v, v, ss);
  }
#pragma unroll
  for (int o = 1; o < 64; o <<= 1) ss += __shfl_xor(ss, o);
  __shared__ float red[4];
  int wid = threadIdx.x >> 6;
  if ((threadIdx.x & 63) == 0) red[wid] = ss;
  __syncthreads();
  float tot = red[0] + red[1] + red[2] + red[3];
  float rs = rsqrtf(tot / (float)D_MODEL + 1e-5f);
  for (int d = threadIdx.x; d < D_MODEL; d += 256) {
    h[t * D_MODEL + d] = ur[d] * rs * w[d];
  }
}

// ---------------------------------------------------------------------------
// dbl GEMM (M=1024, N=80, K=1536) split-K partial kernel (fp32).
#define DBL_NS 8
#define DBL_KSEG (D_INNER / DBL_NS)  // 192
__global__ __launch_bounds__(256) void gemm_dbl_k(
    const float* __restrict__ A, const float* __restrict__ B,
    float* __restrict__ P) {
  __shared__ float As2[16][17];
  __shared__ float Bs2[16][80];
  const int tid = threadIdx.x;
  const int bm = blockIdx.y * 16;
  const int ks0 = blockIdx.x * DBL_KSEG;
  const int tx = tid % 16;
  const int ty = tid / 16;

  float acc[5] = {0.f, 0.f, 0.f, 0.f, 0.f};

  for (int k0 = ks0; k0 < ks0 + DBL_KSEG; k0 += 16) {
    {
      int m = tid / 16, k = tid % 16;
      As2[k][m] = A[(size_t)(bm + m) * D_INNER + k0 + k];
    }
    for (int i = tid; i < 16 * 80; i += 256) {
      int k = i / 80, n = i % 80;
      Bs2[k][n] = B[(size_t)(k0 + k) * 80 + n];
    }
    __syncthreads();
#pragma unroll
    for (int k = 0; k < 16; k++) {
      float ra = As2[k][ty];
#pragma unroll
      for (int j = 0; j < 5; j++) acc[j] = fmaf(ra, Bs2[k][tx * 5 + j], acc[j]);
    }
    __syncthreads();
  }

  float* p = P + ((size_t)blockIdx.x * L_SEQ + bm + ty) * 80 + tx * 5;
#pragma unroll
  for (int j = 0; j < 5; j++) p[j] = acc[j];
}

__global__ __launch_bounds__(256) void dbl_reduce_k(
    const float* __restrict__ P, float* __restrict__ dbl) {
  int i = blockIdx.x * 256 + threadIdx.x;
  float s = 0.f;
#pragma unroll
  for (int ks = 0; ks < DBL_NS; ks++) s += P[(size_t)ks * L_SEQ * 80 + i];
  dbl[i] = s;
}

// ---------------------------------------------------------------------------
__global__ __launch_bounds__(256) void conv_silu_k(
    const float* __restrict__ xz, const float* __restrict__ cw,
    const float* __restrict__ cb, float* __restrict__ xc) {
  int c = blockIdx.x * 256 + threadIdx.x;
  int t = blockIdx.y;
  const float4 w = *(const float4*)(cw + c * 4);
  float acc = cb[c];
  if (t - 3 >= 0) acc = fmaf(xz[(t - 3) * 2 * D_INNER + c], w.x, acc);
  if (t - 2 >= 0) acc = fmaf(xz[(t - 2) * 2 * D_INNER + c], w.y, acc);
  if (t - 1 >= 0) acc = fmaf(xz[(t - 1) * 2 * D_INNER + c], w.z, acc);
  acc = fmaf(xz[t * 2 * D_INNER + c], w.w, acc);
  xc[t * D_INNER + c] = acc / (1.f + __expf(-acc));
}

// ---------------------------------------------------------------------------
// Chunked selective scan (3 phases). Linear recurrence h = dA*h + dBx is
// associative -> split time into NCHUNK chunks for 8x block parallelism.
//
// phase 1: per-chunk P = prod(dA), E = h_end starting from 0. No shuffles.
// grid (NCHUNK, D_INNER/16) x 256; thread = (chunk, channel, state)
__global__ __launch_bounds__(256) void scan1_k(
    const float* __restrict__ dt, const float* __restrict__ xc,
    const float* __restrict__ dbl, const float* __restrict__ A_log,
    float* __restrict__ Pb, float* __restrict__ Eb) {
  __shared__ float s_dt[CS][16];
  __shared__ float s_xc[CS][16];
  __shared__ float s_b[CS][16];
  const int tid = threadIdx.x;
  const int s = tid & 15;
  const int cl = tid >> 4;
  const int c0 = blockIdx.y * 16;
  const int c = c0 + cl;
  const int t0 = blockIdx.x * CS;
  const float a = -__expf(A_log[c * D_STATE + s]);

  const int lc = tid & 15, lt = tid >> 4;
#pragma unroll
  for (int p = 0; p < CS / 16; p++) {
    int t = lt + p * 16;
    size_t gt = (size_t)(t0 + t);
    s_dt[t][lc] = dt[gt * D_INNER + c0 + lc];
    s_xc[t][lc] = xc[gt * D_INNER + c0 + lc];
    s_b[t][lc] = dbl[gt * 80 + DT_RANK + lc];
  }
  __syncthreads();

  float P = 1.f, h = 0.f;
  for (int t = 0; t < CS; t++) {
    float dtv = s_dt[t][cl];
    float dA = __expf(dtv * a);
    P *= dA;
    h = fmaf(dA, h, dtv * s_b[t][s] * s_xc[t][cl]);
  }
  int idx = blockIdx.x * (D_INNER * D_STATE) + c0 * D_STATE + tid;
  Pb[idx] = P;
  Eb[idx] = h;
}

// phase 2: exclusive combine over chunks -> per-chunk start states H[j]
// grid (D_INNER*D_STATE/256) x 256
__global__ __launch_bounds__(256) void scan2_k(
    const float* __restrict__ Pb, const float* __restrict__ Eb,
    float* __restrict__ Hb) {
  int i = blockIdx.x * 256 + threadIdx.x;
  float H = 0.f;
#pragma unroll
  for (int j = 0; j < NCHUNK; j++) {
    int o = j * (D_INNER * D_STATE) + i;
    Hb[o] = H;
    H = fmaf(Pb[o], H, Eb[o]);
  }
}

// phase 3: scan within chunk from start state + skip + silu(z) gate -> y
// grid (NCHUNK, D_INNER/16) x 256
__global__ __launch_bounds__(256) void scan3_k(
    const float* __restrict__ dt, const float* __restrict__ xc,
    const float* __restrict__ dbl, const float* __restrict__ xz,
    const float* __restrict__ A_log, const float* __restrict__ D_skip,
    const float* __restrict__ Hb, float* __restrict__ y) {
  __shared__ float s_dt[CS][16];
  __shared__ float s_xc[CS][16];
  __shared__ float s_z[CS][16];
  __shared__ float s_bc[CS][32];

  const int tid = threadIdx.x;
  const int s = tid & 15;
  const int cl = tid >> 4;
  const int c0 = blockIdx.y * 16;
  const int c = c0 + cl;
  const int t0 = blockIdx.x * CS;

  const float a = -__expf(A_log[c * D_STATE + s]);
  const float Dv = D_skip[c];

  const int lc = tid & 15, lt = tid >> 4;
  const int bj = tid & 31, bt = tid >> 5;
#pragma unroll
  for (int p = 0; p < CS / 16; p++) {
    int t = lt + p * 16;
    size_t gt = (size_t)(t0 + t);
    s_dt[t][lc] = dt[gt * D_INNER + c0 + lc];
    s_xc[t][lc] = xc[gt * D_INNER + c0 + lc];
    s_z[t][lc] = xz[gt * 2 * D_INNER + D_INNER + c0 + lc];
  }
#pragma unroll
  for (int p = 0; p < CS / 8; p++) {
    int t = bt + p * 8;
    s_bc[t][bj] = dbl[(size_t)(t0 + t) * 80 + DT_RANK + bj];
  }
  __syncthreads();

  float hst = Hb[blockIdx.x * (D_INNER * D_STATE) + c0 * D_STATE + tid];

  for (int t = 0; t < CS; t++) {
    float dtv = s_dt[t][cl];
    float xv = s_xc[t][cl];
    float Bv = s_bc[t][s];
    float Cv = s_bc[t][16 + s];
    float dA = __expf(dtv * a);
    hst = fmaf(dA, hst, dtv * Bv * xv);
    float p2 = hst * Cv;
    p2 += __shfl_xor(p2, 1);
    p2 += __shfl_xor(p2, 2);
    p2 += __shfl_xor(p2, 4);
    p2 += __shfl_xor(p2, 8);
    if (s == 0) {
      float zv = s_z[t][cl];
      float sz = zv / (1.f + __expf(-zv));
      y[(size_t)(t0 + t) * D_INNER + c] = (p2 + Dv * xv) * sz;
    }
  }
}

// ---------------------------------------------------------------------------
__global__ __launch_bounds__(256) void final_k(
    const float* __restrict__ u, const float* __restrict__ nfw,
    const float* __restrict__ fcw, const float* __restrict__ fcb,
    float* __restrict__ out) {
  const float* ur = u + (size_t)(L_SEQ - 1) * D_MODEL;
  float ss = 0.f;
  for (int d = threadIdx.x; d < D_MODEL; d += 256) {
    float v = ur[d];
    ss = fmaf(v, v, ss);
  }
#pragma unroll
  for (int o = 1; o < 64; o <<= 1) ss += __shfl_xor(ss, o);
  __shared__ float red[4];
  int wid = threadIdx.x >> 6;
  if ((threadIdx.x & 63) == 0) red[wid] = ss;
  __syncthreads();
  float tot = red[0] + red[1] + red[2] + red[3];
  float rs = rsqrtf(tot / (float)D_MODEL + 1e-5f);
  float a0 = 0.f, a1 = 0.f;
  for (int d = threadIdx.x; d < D_MODEL; d += 256) {
    float hn = ur[d] * rs * nfw[d];
    a0 = fmaf(hn, fcw[d * 2 + 0], a0);
    a1 = fmaf(hn, fcw[d * 2 + 1], a1);
  }
#pragma unroll
  for (int o = 1; o < 64; o <<= 1) {
    a0 += __shfl_xor(a0, o);
    a1 += __shfl_xor(a1, o);
  }
  __shared__ float r0[4], r1[4];
  if ((threadIdx.x & 63) == 0) {
    r0[wid] = a0;
    r1[wid] = a1;
  }
  __syncthreads();
  if (threadIdx.x == 0) out[0] = r0[0] + r0[1] + r0[2] + r0[3] + fcb[0];
  if (threadIdx.x == 1) out[1] = r1[0] + r1[1] + r1[2] + r1[3] + fcb[1];
}

// ---------------------------------------------------------------------------
extern "C" void kernel_launch(void* const* d_in, const int* in_sizes, int n_in,
                              void* d_out, int out_size, void* d_ws,
                              size_t ws_size, hipStream_t stream) {
  const float* x      = (const float*)d_in[0];
  const float* w_enc  = (const float*)d_in[1];
  const float* b_enc  = (const float*)d_in[2];
  const float* norm_w = (const float*)d_in[3];
  const float* in_w   = (const float*)d_in[4];
  const float* conv_w = (const float*)d_in[5];
  const float* conv_b = (const float*)d_in[6];
  const float* xp_w   = (const float*)d_in[7];
  const float* dt_w   = (const float*)d_in[8];
  const float* dt_b   = (const float*)d_in[9];
  const float* A_log  = (const float*)d_in[10];
  const float* D_skip = (const float*)d_in[11];
  const float* out_w  = (const float*)d_in[12];
  const float* nf_w   = (const float*)d_in[13];
  const float* fc_w   = (const float*)d_in[14];
  const float* fc_b   = (const float*)d_in[15];
  float* out = (float*)d_out;

  float* u   = (float*)d_ws;
  float* h   = u   + (size_t)L_SEQ * D_MODEL;
  float* xzb = h   + (size_t)L_SEQ * D_MODEL;
  float* xcb = xzb + (size_t)L_SEQ * 2 * D_INNER;
  float* dbl = xcb + (size_t)L_SEQ * D_INNER;
  float* dtb = dbl + (size_t)L_SEQ * 80;
  float* yb  = dtb + (size_t)L_SEQ * D_INNER;
  // yb doubles as dbl split-K partial buffer (8*1024*80 floats) before scan3.
  // h (1024*768 floats) doubles as P/E/H chunk-scan state (3*196608 floats)
  // after the xz GEMM consumed it.
  float* Pb = h;
  float* Eb = Pb + NCHUNK * D_INNER * D_STATE;
  float* Hb = Eb + NCHUNK * D_INNER * D_STATE;

  encode_k<<<dim3(3, L_SEQ), 256, 0, stream>>>(x, w_enc, b_enc, u);

  for (int l = 0; l < N_LAYERS; l++) {
    const float* in_w_l  = in_w  + (size_t)l * D_MODEL * 2 * D_INNER;
    const float* cw_l    = conv_w + (size_t)l * D_INNER * 4;
    const float* cb_l    = conv_b + (size_t)l * D_INNER;
    const float* xp_w_l  = xp_w  + (size_t)l * D_INNER * 80;
    const float* dt_w_l  = dt_w  + (size_t)l * DT_RANK * D_INNER;
    const float* dt_b_l  = dt_b  + (size_t)l * D_INNER;
    const float* A_log_l = A_log + (size_t)l * D_INNER * D_STATE;
    const float* D_l     = D_skip + (size_t)l * D_INNER;
    const float* out_w_l = out_w + (size_t)l * D_INNER * D_MODEL;

    // h = rmsnorm(u) * norm_w
    rmsnorm_k<<<L_SEQ, 256, 0, stream>>>(u, norm_w + (size_t)l * D_MODEL, h);
    // xz = h @ in_w : M=1024 N=3072 K=768
    gemm_mfma<0><<<dim3(3072 / 64, 1024 / 64), 256, 0, stream>>>(
        h, in_w_l, xzb, D_MODEL, D_MODEL, 2 * D_INNER, 2 * D_INNER, nullptr);
    // xc = silu(conv(xpart) + cb)
    conv_silu_k<<<dim3(6, L_SEQ), 256, 0, stream>>>(xzb, cw_l, cb_l, xcb);
    // dbl = xc @ xp_w : M=1024 N=80 K=1536 (split-K x8 + reduce, fp32)
    gemm_dbl_k<<<dim3(DBL_NS, L_SEQ / 16), 256, 0, stream>>>(xcb, xp_w_l, yb);
    dbl_reduce_k<<<(L_SEQ * 80) / 256, 256, 0, stream>>>(yb, dbl);
    // dt = softplus(dbl[:, :48] @ dt_w + dt_b) : M=1024 N=1536 K=48 (padded)
    gemm_mfma<1><<<dim3(1536 / 64, 1024 / 64), 256, 0, stream>>>(
        dbl, dt_w_l, dtb, DT_RANK, 80, D_INNER, D_INNER, dt_b_l);
    // chunked selective scan + skip + silu(z) gate -> y
    scan1_k<<<dim3(NCHUNK, D_INNER / 16), 256, 0, stream>>>(
        dtb, xcb, dbl, A_log_l, Pb, Eb);
    scan2_k<<<(D_INNER * D_STATE) / 256, 256, 0, stream>>>(Pb, Eb, Hb);
    scan3_k<<<dim3(NCHUNK, D_INNER / 16), 256, 0, stream>>>(
        dtb, xcb, dbl, xzb, A_log_l, D_l, Hb, yb);
    // u += y @ out_w : M=1024 N=768 K=1536
    gemm_mfma<2><<<dim3(768 / 64, 1024 / 64), 256, 0, stream>>>(
        yb, out_w_l, u, D_INNER, D_INNER, D_MODEL, D_MODEL, nullptr);
  }

  final_k<<<1, 256, 0, stream>>>(u, nf_w, fc_w, fc_b, out);
}

// Round 5
// 4691.691 us; speedup vs baseline: 8.1802x; 1.6024x over previous
//
#include <hip/hip_runtime.h>
#include <hip/hip_bf16.h>

#define L_SEQ 1024
#define D_MODEL 768
#define D_INNER 1536
#define D_STATE 16
#define DT_RANK 48
#define N_LAYERS 24
#define NCHUNK 8
#define CS (L_SEQ / NCHUNK)  // 128

typedef __attribute__((ext_vector_type(8))) short short8;
typedef __attribute__((ext_vector_type(4))) float f32x4;

__device__ inline void split1(float v, ushort& hi, ushort& lo) {
  unsigned b = __float_as_uint(v);
  hi = (ushort)(b >> 16);
  float lof = v - __uint_as_float(b & 0xFFFF0000u);
  lo = (ushort)(__float_as_uint(lof) >> 16);
}

// ---------------------------------------------------------------------------
// transpose + split: in [K][N] fp32 (layer l) -> hi/lo [N][Kp] bf16.
// rows k >= K zero-padded. grid (N/64, Kp/64, L) x 256.
__global__ __launch_bounds__(256) void tsplit_k(
    const float* __restrict__ in, ushort* __restrict__ hi,
    ushort* __restrict__ lo, int K, int N, int Kp) {
  __shared__ float tile[64][65];
  const int l = blockIdx.z;
  const float* src = in + (size_t)l * K * N;
  ushort* dh = hi + (size_t)l * N * Kp;
  ushort* dl = lo + (size_t)l * N * Kp;
  const int n0 = blockIdx.x * 64, k0 = blockIdx.y * 64;
  const int tx = threadIdx.x & 63, ty = threadIdx.x >> 6;
#pragma unroll
  for (int rr = 0; rr < 16; rr++) {
    int ky = rr * 4 + ty;
    int k = k0 + ky;
    tile[ky][tx] = (k < K) ? src[(size_t)k * N + n0 + tx] : 0.f;
  }
  __syncthreads();
#pragma unroll
  for (int rr = 0; rr < 16; rr++) {
    int ny = rr * 4 + ty;
    float v = tile[tx][ny];
    ushort h, s;
    split1(v, h, s);
    size_t o = (size_t)(n0 + ny) * Kp + k0 + tx;
    dh[o] = h;
    dl[o] = s;
  }
}

// ---------------------------------------------------------------------------
// split-bf16 3-pass MFMA GEMM with PRE-SPLIT inputs.
// A: hi/lo [M][lda] bf16, B: hi/lo [N][ldb] bf16 (transposed weights).
// C fp32 [M][ldc]. K % 32 == 0. block = 4 waves (2x2), tile 64x64, BK=32.
// EPI: 0 = store, 1 = softplus(c + bias[n]), 2 = C += c
template <int EPI>
__global__ __launch_bounds__(256) void gemm_bf16s(
    const ushort* __restrict__ Ahi, const ushort* __restrict__ Alo, int lda,
    const ushort* __restrict__ Bhi, const ushort* __restrict__ Blo, int ldb,
    float* __restrict__ C, int ldc, int K, const float* __restrict__ bias) {
  constexpr int ST = 40;  // LDS row stride (ushorts) = 80 B
  __shared__ ushort As[2][64 * ST];
  __shared__ ushort Bs[2][64 * ST];

  const int tid = threadIdx.x;
  const int bm = blockIdx.y * 64;
  const int bn = blockIdx.x * 64;
  const int lane = tid & 63;
  const int wid = tid >> 6;
  const int wm = wid & 1, wn = wid >> 1;
  const int r = lane & 15, g = lane >> 4;
  const int row = tid >> 2, ch = tid & 3;  // staging: 64 rows x 4 chunks(16B)

  f32x4 acc[2][2] = {};

  for (int k0 = 0; k0 < K; k0 += 32) {
    __syncthreads();
    *reinterpret_cast<short8*>(&As[0][row * ST + ch * 8]) =
        *reinterpret_cast<const short8*>(&Ahi[(size_t)(bm + row) * lda + k0 + ch * 8]);
    *reinterpret_cast<short8*>(&As[1][row * ST + ch * 8]) =
        *reinterpret_cast<const short8*>(&Alo[(size_t)(bm + row) * lda + k0 + ch * 8]);
    *reinterpret_cast<short8*>(&Bs[0][row * ST + ch * 8]) =
        *reinterpret_cast<const short8*>(&Bhi[(size_t)(bn + row) * ldb + k0 + ch * 8]);
    *reinterpret_cast<short8*>(&Bs[1][row * ST + ch * 8]) =
        *reinterpret_cast<const short8*>(&Blo[(size_t)(bn + row) * ldb + k0 + ch * 8]);
    __syncthreads();

    short8 a_hi[2], a_lo[2], b_hi[2], b_lo[2];
#pragma unroll
    for (int m = 0; m < 2; m++) {
      int rw = wm * 32 + m * 16 + r;
      a_hi[m] = *reinterpret_cast<short8*>(&As[0][rw * ST + g * 8]);
      a_lo[m] = *reinterpret_cast<short8*>(&As[1][rw * ST + g * 8]);
    }
#pragma unroll
    for (int n = 0; n < 2; n++) {
      int rw = wn * 32 + n * 16 + r;
      b_hi[n] = *reinterpret_cast<short8*>(&Bs[0][rw * ST + g * 8]);
      b_lo[n] = *reinterpret_cast<short8*>(&Bs[1][rw * ST + g * 8]);
    }
#pragma unroll
    for (int m = 0; m < 2; m++)
#pragma unroll
      for (int n = 0; n < 2; n++) {
        acc[m][n] = __builtin_amdgcn_mfma_f32_16x16x32_bf16(
            a_hi[m], b_hi[n], acc[m][n], 0, 0, 0);
        acc[m][n] = __builtin_amdgcn_mfma_f32_16x16x32_bf16(
            a_hi[m], b_lo[n], acc[m][n], 0, 0, 0);
        acc[m][n] = __builtin_amdgcn_mfma_f32_16x16x32_bf16(
            a_lo[m], b_hi[n], acc[m][n], 0, 0, 0);
      }
  }

#pragma unroll
  for (int m = 0; m < 2; m++) {
#pragma unroll
    for (int n = 0; n < 2; n++) {
      int row0 = bm + wm * 32 + m * 16 + g * 4;
      int col = bn + wn * 32 + n * 16 + r;
#pragma unroll
      for (int j = 0; j < 4; j++) {
        size_t idx = (size_t)(row0 + j) * ldc + col;
        float v = acc[m][n][j];
        if (EPI == 0) {
          C[idx] = v;
        } else if (EPI == 1) {
          v += bias[col];
          C[idx] = (v > 20.f) ? v : log1pf(__expf(v));
        } else {
          C[idx] += v;
        }
      }
    }
  }
}

// ---------------------------------------------------------------------------
__global__ __launch_bounds__(256) void encode_k(
    const float* __restrict__ x, const float* __restrict__ w_enc,
    const float* __restrict__ b_enc, float* __restrict__ u) {
  int d = blockIdx.x * 256 + threadIdx.x;
  int t = blockIdx.y;
  const float4 xv = *(const float4*)(x + t * 4);
  float acc = b_enc[d];
  acc = fmaf(xv.x, w_enc[0 * D_MODEL + d], acc);
  acc = fmaf(xv.y, w_enc[1 * D_MODEL + d], acc);
  acc = fmaf(xv.z, w_enc[2 * D_MODEL + d], acc);
  acc = fmaf(xv.w, w_enc[3 * D_MODEL + d], acc);
  u[t * D_MODEL + d] = acc;
}

// ---------------------------------------------------------------------------
// rmsnorm with split-bf16 output planes
__global__ __launch_bounds__(256) void rmsnorm_split_k(
    const float* __restrict__ u, const float* __restrict__ w,
    ushort* __restrict__ hh, ushort* __restrict__ hl) {
  int t = blockIdx.x;
  const float* ur = u + t * D_MODEL;
  float ss = 0.f;
  for (int d = threadIdx.x; d < D_MODEL; d += 256) {
    float v = ur[d];
    ss = fmaf(v, v, ss);
  }
#pragma unroll
  for (int o = 1; o < 64; o <<= 1) ss += __shfl_xor(ss, o);
  __shared__ float red[4];
  int wid = threadIdx.x >> 6;
  if ((threadIdx.x & 63) == 0) red[wid] = ss;
  __syncthreads();
  float tot = red[0] + red[1] + red[2] + red[3];
  float rs = rsqrtf(tot / (float)D_MODEL + 1e-5f);
  for (int d = threadIdx.x; d < D_MODEL; d += 256) {
    float v = ur[d] * rs * w[d];
    ushort h, s;
    split1(v, h, s);
    hh[t * D_MODEL + d] = h;
    hl[t * D_MODEL + d] = s;
  }
}

// ---------------------------------------------------------------------------
// dbl GEMM (M=1024, N=80, K=1536) split-K partial kernel (fp32).
#define DBL_NS 8
#define DBL_KSEG (D_INNER / DBL_NS)  // 192
__global__ __launch_bounds__(256) void gemm_dbl_k(
    const float* __restrict__ A, const float* __restrict__ B,
    float* __restrict__ P) {
  __shared__ float As2[16][17];
  __shared__ float Bs2[16][80];
  const int tid = threadIdx.x;
  const int bm = blockIdx.y * 16;
  const int ks0 = blockIdx.x * DBL_KSEG;
  const int tx = tid % 16;
  const int ty = tid / 16;

  float acc[5] = {0.f, 0.f, 0.f, 0.f, 0.f};

  for (int k0 = ks0; k0 < ks0 + DBL_KSEG; k0 += 16) {
    {
      int m = tid / 16, k = tid % 16;
      As2[k][m] = A[(size_t)(bm + m) * D_INNER + k0 + k];
    }
    for (int i = tid; i < 16 * 80; i += 256) {
      int k = i / 80, n = i % 80;
      Bs2[k][n] = B[(size_t)(k0 + k) * 80 + n];
    }
    __syncthreads();
#pragma unroll
    for (int k = 0; k < 16; k++) {
      float ra = As2[k][ty];
#pragma unroll
      for (int j = 0; j < 5; j++) acc[j] = fmaf(ra, Bs2[k][tx * 5 + j], acc[j]);
    }
    __syncthreads();
  }

  float* p = P + ((size_t)blockIdx.x * L_SEQ + bm + ty) * 80 + tx * 5;
#pragma unroll
  for (int j = 0; j < 5; j++) p[j] = acc[j];
}

// reduce + emit dtA split planes [1024][64] (cols 48..63 zero)
__global__ __launch_bounds__(256) void dbl_reduce_k(
    const float* __restrict__ P, float* __restrict__ dbl,
    ushort* __restrict__ dah, ushort* __restrict__ dal) {
  int i = blockIdx.x * 256 + threadIdx.x;  // 0..81919
  float s = 0.f;
#pragma unroll
  for (int ks = 0; ks < DBL_NS; ks++) s += P[(size_t)ks * L_SEQ * 80 + i];
  dbl[i] = s;
  int rowi = i / 80, col = i % 80;
  if (col < DT_RANK) {
    ushort h, lo;
    split1(s, h, lo);
    dah[rowi * 64 + col] = h;
    dal[rowi * 64 + col] = lo;
  } else if (col >= 64) {  // cover pad cols 48..63
    dah[rowi * 64 + col - 16] = 0;
    dal[rowi * 64 + col - 16] = 0;
  }
}

// ---------------------------------------------------------------------------
__global__ __launch_bounds__(256) void conv_silu_k(
    const float* __restrict__ xz, const float* __restrict__ cw,
    const float* __restrict__ cb, float* __restrict__ xc) {
  int c = blockIdx.x * 256 + threadIdx.x;
  int t = blockIdx.y;
  const float4 w = *(const float4*)(cw + c * 4);
  float acc = cb[c];
  if (t - 3 >= 0) acc = fmaf(xz[(t - 3) * 2 * D_INNER + c], w.x, acc);
  if (t - 2 >= 0) acc = fmaf(xz[(t - 2) * 2 * D_INNER + c], w.y, acc);
  if (t - 1 >= 0) acc = fmaf(xz[(t - 1) * 2 * D_INNER + c], w.z, acc);
  acc = fmaf(xz[t * 2 * D_INNER + c], w.w, acc);
  xc[t * D_INNER + c] = acc / (1.f + __expf(-acc));
}

// ---------------------------------------------------------------------------
// Chunked selective scan (3 phases).
__global__ __launch_bounds__(256) void scan1_k(
    const float* __restrict__ dt, const float* __restrict__ xc,
    const float* __restrict__ dbl, const float* __restrict__ A_log,
    float* __restrict__ Pb, float* __restrict__ Eb) {
  __shared__ float s_dt[CS][16];
  __shared__ float s_xc[CS][16];
  __shared__ float s_b[CS][16];
  const int tid = threadIdx.x;
  const int s = tid & 15;
  const int cl = tid >> 4;
  const int c0 = blockIdx.y * 16;
  const int c = c0 + cl;
  const int t0 = blockIdx.x * CS;
  const float a = -__expf(A_log[c * D_STATE + s]);

  const int lc = tid & 15, lt = tid >> 4;
#pragma unroll
  for (int p = 0; p < CS / 16; p++) {
    int t = lt + p * 16;
    size_t gt = (size_t)(t0 + t);
    s_dt[t][lc] = dt[gt * D_INNER + c0 + lc];
    s_xc[t][lc] = xc[gt * D_INNER + c0 + lc];
    s_b[t][lc] = dbl[gt * 80 + DT_RANK + lc];
  }
  __syncthreads();

  float P = 1.f, h = 0.f;
  for (int t = 0; t < CS; t++) {
    float dtv = s_dt[t][cl];
    float dA = __expf(dtv * a);
    P *= dA;
    h = fmaf(dA, h, dtv * s_b[t][s] * s_xc[t][cl]);
  }
  int idx = blockIdx.x * (D_INNER * D_STATE) + c0 * D_STATE + tid;
  Pb[idx] = P;
  Eb[idx] = h;
}

__global__ __launch_bounds__(256) void scan2_k(
    const float* __restrict__ Pb, const float* __restrict__ Eb,
    float* __restrict__ Hb) {
  int i = blockIdx.x * 256 + threadIdx.x;
  float H = 0.f;
#pragma unroll
  for (int j = 0; j < NCHUNK; j++) {
    int o = j * (D_INNER * D_STATE) + i;
    Hb[o] = H;
    H = fmaf(Pb[o], H, Eb[o]);
  }
}

// phase 3 -> writes y as split bf16 planes (feeds out-proj GEMM)
__global__ __launch_bounds__(256) void scan3_k(
    const float* __restrict__ dt, const float* __restrict__ xc,
    const float* __restrict__ dbl, const float* __restrict__ xz,
    const float* __restrict__ A_log, const float* __restrict__ D_skip,
    const float* __restrict__ Hb, ushort* __restrict__ yh,
    ushort* __restrict__ yl) {
  __shared__ float s_dt[CS][16];
  __shared__ float s_xc[CS][16];
  __shared__ float s_z[CS][16];
  __shared__ float s_bc[CS][32];

  const int tid = threadIdx.x;
  const int s = tid & 15;
  const int cl = tid >> 4;
  const int c0 = blockIdx.y * 16;
  const int c = c0 + cl;
  const int t0 = blockIdx.x * CS;

  const float a = -__expf(A_log[c * D_STATE + s]);
  const float Dv = D_skip[c];

  const int lc = tid & 15, lt = tid >> 4;
  const int bj = tid & 31, bt = tid >> 5;
#pragma unroll
  for (int p = 0; p < CS / 16; p++) {
    int t = lt + p * 16;
    size_t gt = (size_t)(t0 + t);
    s_dt[t][lc] = dt[gt * D_INNER + c0 + lc];
    s_xc[t][lc] = xc[gt * D_INNER + c0 + lc];
    s_z[t][lc] = xz[gt * 2 * D_INNER + D_INNER + c0 + lc];
  }
#pragma unroll
  for (int p = 0; p < CS / 8; p++) {
    int t = bt + p * 8;
    s_bc[t][bj] = dbl[(size_t)(t0 + t) * 80 + DT_RANK + bj];
  }
  __syncthreads();

  float hst = Hb[blockIdx.x * (D_INNER * D_STATE) + c0 * D_STATE + tid];

  for (int t = 0; t < CS; t++) {
    float dtv = s_dt[t][cl];
    float xv = s_xc[t][cl];
    float Bv = s_bc[t][s];
    float Cv = s_bc[t][16 + s];
    float dA = __expf(dtv * a);
    hst = fmaf(dA, hst, dtv * Bv * xv);
    float p2 = hst * Cv;
    p2 += __shfl_xor(p2, 1);
    p2 += __shfl_xor(p2, 2);
    p2 += __shfl_xor(p2, 4);
    p2 += __shfl_xor(p2, 8);
    if (s == 0) {
      float zv = s_z[t][cl];
      float sz = zv / (1.f + __expf(-zv));
      float yv = (p2 + Dv * xv) * sz;
      ushort h, lo;
      split1(yv, h, lo);
      size_t o = (size_t)(t0 + t) * D_INNER + c;
      yh[o] = h;
      yl[o] = lo;
    }
  }
}

// ---------------------------------------------------------------------------
__global__ __launch_bounds__(256) void final_k(
    const float* __restrict__ u, const float* __restrict__ nfw,
    const float* __restrict__ fcw, const float* __restrict__ fcb,
    float* __restrict__ out) {
  const float* ur = u + (size_t)(L_SEQ - 1) * D_MODEL;
  float ss = 0.f;
  for (int d = threadIdx.x; d < D_MODEL; d += 256) {
    float v = ur[d];
    ss = fmaf(v, v, ss);
  }
#pragma unroll
  for (int o = 1; o < 64; o <<= 1) ss += __shfl_xor(ss, o);
  __shared__ float red[4];
  int wid = threadIdx.x >> 6;
  if ((threadIdx.x & 63) == 0) red[wid] = ss;
  __syncthreads();
  float tot = red[0] + red[1] + red[2] + red[3];
  float rs = rsqrtf(tot / (float)D_MODEL + 1e-5f);
  float a0 = 0.f, a1 = 0.f;
  for (int d = threadIdx.x; d < D_MODEL; d += 256) {
    float hn = ur[d] * rs * nfw[d];
    a0 = fmaf(hn, fcw[d * 2 + 0], a0);
    a1 = fmaf(hn, fcw[d * 2 + 1], a1);
  }
#pragma unroll
  for (int o = 1; o < 64; o <<= 1) {
    a0 += __shfl_xor(a0, o);
    a1 += __shfl_xor(a1, o);
  }
  __shared__ float r0[4], r1[4];
  if ((threadIdx.x & 63) == 0) {
    r0[wid] = a0;
    r1[wid] = a1;
  }
  __syncthreads();
  if (threadIdx.x == 0) out[0] = r0[0] + r0[1] + r0[2] + r0[3] + fcb[0];
  if (threadIdx.x == 1) out[1] = r1[0] + r1[1] + r1[2] + r1[3] + fcb[1];
}

// ---------------------------------------------------------------------------
extern "C" void kernel_launch(void* const* d_in, const int* in_sizes, int n_in,
                              void* d_out, int out_size, void* d_ws,
                              size_t ws_size, hipStream_t stream) {
  const float* x      = (const float*)d_in[0];
  const float* w_enc  = (const float*)d_in[1];
  const float* b_enc  = (const float*)d_in[2];
  const float* norm_w = (const float*)d_in[3];
  const float* in_w   = (const float*)d_in[4];
  const float* conv_w = (const float*)d_in[5];
  const float* conv_b = (const float*)d_in[6];
  const float* xp_w   = (const float*)d_in[7];
  const float* dt_w   = (const float*)d_in[8];
  const float* dt_b   = (const float*)d_in[9];
  const float* A_log  = (const float*)d_in[10];
  const float* D_skip = (const float*)d_in[11];
  const float* out_w  = (const float*)d_in[12];
  const float* nf_w   = (const float*)d_in[13];
  const float* fc_w   = (const float*)d_in[14];
  const float* fc_b   = (const float*)d_in[15];
  float* out = (float*)d_out;

  // ---- fp32 workspace
  float* u   = (float*)d_ws;
  float* h   = u   + (size_t)L_SEQ * D_MODEL;   // dead fp32 slot -> P/E/H
  float* xzb = h   + (size_t)L_SEQ * D_MODEL;
  float* xcb = xzb + (size_t)L_SEQ * 2 * D_INNER;
  float* dbl = xcb + (size_t)L_SEQ * D_INNER;
  float* dtb = dbl + (size_t)L_SEQ * 80;
  float* yb  = dtb + (size_t)L_SEQ * D_INNER;   // dbl split-K partials
  float* fend = yb + (size_t)L_SEQ * D_INNER;
  float* Pb = h;
  float* Eb = Pb + NCHUNK * D_INNER * D_STATE;
  float* Hb = Eb + NCHUNK * D_INNER * D_STATE;

  // ---- bf16 plane workspace (activations + repacked weights)
  ushort* us = (ushort*)fend;
  ushort* hh  = us;                      // [1024][768]
  ushort* hl  = hh + (size_t)L_SEQ * D_MODEL;
  ushort* dah = hl + (size_t)L_SEQ * D_MODEL;   // [1024][64]
  ushort* dal = dah + (size_t)L_SEQ * 64;
  ushort* yh  = dal + (size_t)L_SEQ * 64;       // [1024][1536]
  ushort* yl  = yh + (size_t)L_SEQ * D_INNER;
  ushort* wxh = yl + (size_t)L_SEQ * D_INNER;   // in_w^T  [24][3072][768]
  ushort* wxl = wxh + (size_t)N_LAYERS * 2 * D_INNER * D_MODEL;
  ushort* wdh = wxl + (size_t)N_LAYERS * 2 * D_INNER * D_MODEL;  // dt_w^T [24][1536][64]
  ushort* wdl = wdh + (size_t)N_LAYERS * D_INNER * 64;
  ushort* woh = wdl + (size_t)N_LAYERS * D_INNER * 64;  // out_w^T [24][768][1536]
  ushort* wol = woh + (size_t)N_LAYERS * D_MODEL * D_INNER;

  // ---- one-time per call: weight repack (transpose + bf16 split)
  tsplit_k<<<dim3(2 * D_INNER / 64, D_MODEL / 64, N_LAYERS), 256, 0, stream>>>(
      in_w, wxh, wxl, D_MODEL, 2 * D_INNER, D_MODEL);
  tsplit_k<<<dim3(D_INNER / 64, 1, N_LAYERS), 256, 0, stream>>>(
      dt_w, wdh, wdl, DT_RANK, D_INNER, 64);
  tsplit_k<<<dim3(D_MODEL / 64, D_INNER / 64, N_LAYERS), 256, 0, stream>>>(
      out_w, woh, wol, D_INNER, D_MODEL, D_INNER);

  encode_k<<<dim3(3, L_SEQ), 256, 0, stream>>>(x, w_enc, b_enc, u);

  for (int l = 0; l < N_LAYERS; l++) {
    const float* cw_l    = conv_w + (size_t)l * D_INNER * 4;
    const float* cb_l    = conv_b + (size_t)l * D_INNER;
    const float* xp_w_l  = xp_w  + (size_t)l * D_INNER * 80;
    const float* dt_b_l  = dt_b  + (size_t)l * D_INNER;
    const float* A_log_l = A_log + (size_t)l * D_INNER * D_STATE;
    const float* D_l     = D_skip + (size_t)l * D_INNER;
    const ushort* wxh_l = wxh + (size_t)l * 2 * D_INNER * D_MODEL;
    const ushort* wxl_l = wxl + (size_t)l * 2 * D_INNER * D_MODEL;
    const ushort* wdh_l = wdh + (size_t)l * D_INNER * 64;
    const ushort* wdl_l = wdl + (size_t)l * D_INNER * 64;
    const ushort* woh_l = woh + (size_t)l * D_MODEL * D_INNER;
    const ushort* wol_l = wol + (size_t)l * D_MODEL * D_INNER;

    // h(hi/lo) = rmsnorm(u) * norm_w
    rmsnorm_split_k<<<L_SEQ, 256, 0, stream>>>(
        u, norm_w + (size_t)l * D_MODEL, hh, hl);
    // xz = h @ in_w : M=1024 N=3072 K=768
    gemm_bf16s<0><<<dim3(2 * D_INNER / 64, L_SEQ / 64), 256, 0, stream>>>(
        hh, hl, D_MODEL, wxh_l, wxl_l, D_MODEL, xzb, 2 * D_INNER, D_MODEL,
        nullptr);
    // xc = silu(conv(xpart) + cb)
    conv_silu_k<<<dim3(6, L_SEQ), 256, 0, stream>>>(xzb, cw_l, cb_l, xcb);
    // dbl = xc @ xp_w : M=1024 N=80 K=1536 (split-K x8 + reduce, fp32)
    gemm_dbl_k<<<dim3(DBL_NS, L_SEQ / 16), 256, 0, stream>>>(xcb, xp_w_l, yb);
    dbl_reduce_k<<<(L_SEQ * 80) / 256, 256, 0, stream>>>(yb, dbl, dah, dal);
    // dt = softplus(dbl[:, :48] @ dt_w + dt_b) : K=48 padded to 64
    gemm_bf16s<1><<<dim3(D_INNER / 64, L_SEQ / 64), 256, 0, stream>>>(
        dah, dal, 64, wdh_l, wdl_l, 64, dtb, D_INNER, 64, dt_b_l);
    // chunked selective scan + skip + silu(z) gate -> y (split planes)
    scan1_k<<<dim3(NCHUNK, D_INNER / 16), 256, 0, stream>>>(
        dtb, xcb, dbl, A_log_l, Pb, Eb);
    scan2_k<<<(D_INNER * D_STATE) / 256, 256, 0, stream>>>(Pb, Eb, Hb);
    scan3_k<<<dim3(NCHUNK, D_INNER / 16), 256, 0, stream>>>(
        dtb, xcb, dbl, xzb, A_log_l, D_l, Hb, yh, yl);
    // u += y @ out_w : M=1024 N=768 K=1536
    gemm_bf16s<2><<<dim3(D_MODEL / 64, L_SEQ / 64), 256, 0, stream>>>(
        yh, yl, D_INNER, woh_l, wol_l, D_INNER, u, D_MODEL, D_INNER, nullptr);
  }

  final_k<<<1, 256, 0, stream>>>(u, nf_w, fc_w, fc_b, out);
}